// Round 5
// baseline (804.997 us; speedup 1.0000x reference)
//
#include <hip/hip_runtime.h>
#include <math.h>

#define HID 64
#define EMB 8
#define SDEC 20
#define TSEQ 2048

typedef short short8 __attribute__((ext_vector_type(8)));
typedef float f32x4 __attribute__((ext_vector_type(4)));
union U16x8 { unsigned u[4]; short8 s; uint4 v; };

#define SSIG (-1.44269504088896f)   /* -log2(e): sigmoid(x)=rcp(1+exp2(SSIG*x)) */
#define STAN ( 2.88539008177793f)   /* 2*log2(e): tanh(v)=1-2*rcp(1+exp2(STAN*v)) */

__device__ __forceinline__ float fexp2(float x){ return __builtin_amdgcn_exp2f(x); }
__device__ __forceinline__ float frcp(float x){ return __builtin_amdgcn_rcpf(x); }
__device__ __forceinline__ unsigned cvt_pk_bf16(float lo, float hi){
    unsigned r; asm("v_cvt_pk_bf16_f32 %0, %1, %2" : "=v"(r) : "v"(lo), "v"(hi)); return r;
}
__device__ __forceinline__ short8 pack_row8(const float* p, float s){
    U16x8 t;
    #pragma unroll
    for (int i = 0; i < 4; ++i) t.u[i] = cvt_pk_bf16(s*p[2*i], s*p[2*i+1]);
    return t.s;
}
// producer->consumer LDS handoff: wait own ds ops retired, rendezvous, no vmcnt drain
__device__ __forceinline__ void group_barrier(){
    asm volatile("s_waitcnt lgkmcnt(0)" ::: "memory");
    __builtin_amdgcn_s_barrier();
    asm volatile("" ::: "memory");
}

extern "C" __global__ __launch_bounds__(256, 1) void gru_mfma_kernel(
    const float* __restrict__ in,
    const float* __restrict__ velW, const float* __restrict__ velb,
    const float* __restrict__ eWih, const float* __restrict__ eWhh,
    const float* __restrict__ ebih, const float* __restrict__ ebhh,
    const float* __restrict__ dWih, const float* __restrict__ dWhh,
    const float* __restrict__ dbih, const float* __restrict__ dbhh,
    const float* __restrict__ linW, const float* __restrict__ linb,
    float* __restrict__ out)
{
    __shared__ __align__(16) unsigned char smem[4096];   // 2 bufs x 16 batch x 128B
    const int tid  = (int)threadIdx.x;
    const int lane = tid & 63;
    const int w    = tid >> 6;       // wave 0..3, owns j in [16w, 16w+16)
    const int c    = lane & 15;      // batch col within group
    const int q    = lane >> 4;      // quarter group
    const int b    = (int)blockIdx.x * 16 + c;
    const float* sc = in + (size_t)b * (TSEQ * 2);
    const unsigned qm = (q == 0) ? 0xffffffffu : 0u;  // gi B-vec only in k=0..7 lanes

    // ---- encoder embedding base: eb[k] = vel_b[k] + PE[b][k]
    float eb[EMB];
    #pragma unroll
    for (int i = 0; i < 4; ++i) {
        float div = __expf((float)(2*i) * -1.1512925464970229f); // -ln(10000)/8
        float arg = (float)b * div;
        eb[2*i]   = velb[2*i]   + __sinf(arg);
        eb[2*i+1] = velb[2*i+1] + __cosf(arg);
    }

    // ---- dx/dy-independent gate constants (fp32, used as MFMA C-in), j = 16w+4q+r
    f32x4 CRv, CZv, CNv, BHv;
    #pragma unroll
    for (int r_ = 0; r_ < 4; ++r_) {
        int j = 16*w + 4*q + r_;
        #pragma unroll
        for (int g = 0; g < 3; ++g) {
            int row = g*HID + j;
            float cc = ebih[row];
            #pragma unroll
            for (int k = 0; k < EMB; ++k) cc += eWih[row*EMB + k] * eb[k];
            if      (g == 0) CRv[r_] = SSIG*(cc + ebhh[j]);
            else if (g == 1) CZv[r_] = SSIG*(cc + ebhh[HID+j]);
            else           { CNv[r_] = STAN*cc; BHv[r_] = STAN*ebhh[2*HID+j]; }
        }
    }

    // ---- gi A-fragments: per A-row j' = 16w+c, k rows [A, B, A, B] (dxh,dyh,dxl,dyl)
    short8 GIR, GIZ, GIN;
    {
        int jj = 16*w + c;
        #pragma unroll
        for (int g = 0; g < 3; ++g) {
            float a = 0.f, bb = 0.f;
            #pragma unroll
            for (int k = 0; k < EMB; ++k) {
                float wv = eWih[(g*HID + jj)*EMB + k];
                a  += wv * velW[2*k];
                bb += wv * velW[2*k+1];
            }
            float s = (g == 2) ? STAN : SSIG;
            U16x8 t;
            t.u[0] = cvt_pk_bf16(s*a, s*bb) & qm;
            t.u[1] = t.u[0];
            t.u[2] = 0; t.u[3] = 0;
            if      (g == 0) GIR = t.s;
            else if (g == 1) GIZ = t.s;
            else             GIN = t.s;
        }
    }

    // ---- h A-fragments (pre-scaled): tile (g*4+w), row=16*tile+c, k=32kk+8q+i
    short8 AF0k0 = pack_row8(eWhh + (16*(0+w)+c)*HID      + 8*q, SSIG);
    short8 AF0k1 = pack_row8(eWhh + (16*(0+w)+c)*HID + 32 + 8*q, SSIG);
    short8 AF1k0 = pack_row8(eWhh + (16*(4+w)+c)*HID      + 8*q, SSIG);
    short8 AF1k1 = pack_row8(eWhh + (16*(4+w)+c)*HID + 32 + 8*q, SSIG);
    short8 AF2k0 = pack_row8(eWhh + (16*(8+w)+c)*HID      + 8*q, STAN);
    short8 AF2k1 = pack_row8(eWhh + (16*(8+w)+c)*HID + 32 + 8*q, STAN);

    // ---- LDS addresses (XOR-swizzled within each 128B batch-row; +64 inside the XOR!)
    const int swz = (c & 7) << 4;
    unsigned char* wptr        = smem + c*128 + ((32*w + 8*q) ^ swz);  // write: 4 h (8B)
    const unsigned char* rptr0 = smem + c*128 + ((16*q     ) ^ swz);   // B-frag kk=0
    const unsigned char* rptr1 = smem + c*128 + ((16*q + 64) ^ swz);   // B-frag kk=1

    *(uint2*)(wptr) = make_uint2(0u, 0u);   // h0 = 0 into buf0
    group_barrier();

    f32x4 hv = {0.f, 0.f, 0.f, 0.f};

#define STEP(BUF, DX, DY) { \
    U16x8 b0_, b1_; \
    b0_.v = *(const uint4*)(rptr0 + (BUF)*2048); \
    b1_.v = *(const uint4*)(rptr1 + (BUF)*2048); \
    const float dx_ = (DX), dy_ = (DY); \
    unsigned w0_ = cvt_pk_bf16(dx_, dy_); \
    float dxh_ = __uint_as_float(w0_ << 16); \
    float dyh_ = __uint_as_float(w0_ & 0xffff0000u); \
    unsigned w1_ = cvt_pk_bf16(dx_ - dxh_, dy_ - dyh_); \
    U16x8 gv_; gv_.u[0] = w0_ & qm; gv_.u[1] = w1_ & qm; gv_.u[2] = 0; gv_.u[3] = 0; \
    f32x4 aR_ = __builtin_amdgcn_mfma_f32_16x16x32_bf16(GIR, gv_.s, CRv, 0,0,0); \
    f32x4 aZ_ = __builtin_amdgcn_mfma_f32_16x16x32_bf16(GIZ, gv_.s, CZv, 0,0,0); \
    f32x4 aG_ = __builtin_amdgcn_mfma_f32_16x16x32_bf16(GIN, gv_.s, CNv, 0,0,0); \
    aR_ = __builtin_amdgcn_mfma_f32_16x16x32_bf16(AF0k0, b0_.s, aR_, 0,0,0); \
    aZ_ = __builtin_amdgcn_mfma_f32_16x16x32_bf16(AF1k0, b0_.s, aZ_, 0,0,0); \
    f32x4 aN_ = __builtin_amdgcn_mfma_f32_16x16x32_bf16(AF2k0, b0_.s, BHv, 0,0,0); \
    aR_ = __builtin_amdgcn_mfma_f32_16x16x32_bf16(AF0k1, b1_.s, aR_, 0,0,0); \
    aZ_ = __builtin_amdgcn_mfma_f32_16x16x32_bf16(AF1k1, b1_.s, aZ_, 0,0,0); \
    aN_ = __builtin_amdgcn_mfma_f32_16x16x32_bf16(AF2k1, b1_.s, aN_, 0,0,0); \
    _Pragma("unroll") \
    for (int r_ = 0; r_ < 4; ++r_) { \
        float rr = frcp(1.0f + fexp2(aR_[r_])); \
        float zz = frcp(1.0f + fexp2(aZ_[r_])); \
        float uu = fmaf(rr, aN_[r_], aG_[r_]); \
        float dd = frcp(1.0f + fexp2(uu)); \
        float nn = fmaf(-2.0f, dd, 1.0f); \
        hv[r_] = fmaf(zz, hv[r_] - nn, nn); \
    } \
    *(uint2*)(wptr + ((BUF)^1)*2048) = make_uint2(cvt_pk_bf16(hv[0],hv[1]), cvt_pk_bf16(hv[2],hv[3])); \
    group_barrier(); }

    // ================= encoder: 2047 steps, 4 per iter =================
    const float4* gp = (const float4*)(sc);
    float4 P0 = gp[0], P1 = gp[1];
    gp += 2;
    for (int k = 0; k < (TSEQ/4) - 1; ++k) {       // 511 iters -> steps 0..2043
        float4 N0 = gp[0], N1 = gp[1];             // prefetch points 4k+4..4k+7
        gp += 2;
        STEP(0, P0.z - P0.x, P0.w - P0.y);
        STEP(1, P1.x - P0.z, P1.y - P0.w);
        STEP(0, P1.z - P1.x, P1.w - P1.y);
        STEP(1, N0.x - P1.z, N0.y - P1.w);
        P0 = N0; P1 = N1;
    }
    // tail: P0,P1 = points 2044..2047, steps 2044..2046
    STEP(0, P0.z - P0.x, P0.w - P0.y);
    STEP(1, P1.x - P0.z, P1.y - P0.w);
    STEP(0, P1.z - P1.x, P1.w - P1.y);
    // final h now in buf1

    // ================= decoder setup (same folded structure, dec weights) =======
    float px0 = P1.z - P1.x, px1 = P1.w - P1.y;    // diffs[:, -1]
    float off0 = P1.z, off1 = P1.w;                // input_seq[:, -1, :2]

    #pragma unroll
    for (int r_ = 0; r_ < 4; ++r_) {
        int j = 16*w + 4*q + r_;
        #pragma unroll
        for (int g = 0; g < 3; ++g) {
            int row = g*HID + j;
            float cc = dbih[row];
            #pragma unroll
            for (int k = 0; k < EMB; ++k) cc += dWih[row*EMB + k] * velb[k]; // no PE
            if      (g == 0) CRv[r_] = SSIG*(cc + dbhh[j]);
            else if (g == 1) CZv[r_] = SSIG*(cc + dbhh[HID+j]);
            else           { CNv[r_] = STAN*cc; BHv[r_] = STAN*dbhh[2*HID+j]; }
        }
    }
    {
        int jj = 16*w + c;
        #pragma unroll
        for (int g = 0; g < 3; ++g) {
            float a = 0.f, bb = 0.f;
            #pragma unroll
            for (int k = 0; k < EMB; ++k) {
                float wv = dWih[(g*HID + jj)*EMB + k];
                a  += wv * velW[2*k];
                bb += wv * velW[2*k+1];
            }
            float s = (g == 2) ? STAN : SSIG;
            U16x8 t;
            t.u[0] = cvt_pk_bf16(s*a, s*bb) & qm;
            t.u[1] = t.u[0];
            t.u[2] = 0; t.u[3] = 0;
            if      (g == 0) GIR = t.s;
            else if (g == 1) GIZ = t.s;
            else             GIN = t.s;
        }
    }
    AF0k0 = pack_row8(dWhh + (16*(0+w)+c)*HID      + 8*q, SSIG);
    AF0k1 = pack_row8(dWhh + (16*(0+w)+c)*HID + 32 + 8*q, SSIG);
    AF1k0 = pack_row8(dWhh + (16*(4+w)+c)*HID      + 8*q, SSIG);
    AF1k1 = pack_row8(dWhh + (16*(4+w)+c)*HID + 32 + 8*q, SSIG);
    AF2k0 = pack_row8(dWhh + (16*(8+w)+c)*HID      + 8*q, STAN);
    AF2k1 = pack_row8(dWhh + (16*(8+w)+c)*HID + 32 + 8*q, STAN);

    float lw0[16], lw1[16];
    #pragma unroll
    for (int u = 0; u < 16; ++u) {
        lw0[u] = linW[16*q + u];
        lw1[u] = linW[HID + 16*q + u];
    }
    const float lb0 = linb[0], lb1 = linb[1];
    float* outp = out + (size_t)b * SDEC * 2;
    const unsigned char* xptr0 = smem + c*128 + ((32*q) ^ swz);
    const unsigned char* xptr1 = smem + c*128 + ((32*q + 16) ^ swz);

#define XPROJ(BUFN, S) { \
    U16x8 xu0, xu1; \
    xu0.v = *(const uint4*)(xptr0 + (BUFN)*2048); \
    xu1.v = *(const uint4*)(xptr1 + (BUFN)*2048); \
    float s0 = 0.f, s1 = 0.f; \
    _Pragma("unroll") \
    for (int i = 0; i < 8; ++i) { \
        unsigned dw = (i < 4) ? xu0.u[i] : xu1.u[i-4]; \
        float hlo = __uint_as_float(dw << 16); \
        float hhi = __uint_as_float(dw & 0xffff0000u); \
        s0 = fmaf(hlo, lw0[2*i], fmaf(hhi, lw0[2*i+1], s0)); \
        s1 = fmaf(hlo, lw1[2*i], fmaf(hhi, lw1[2*i+1], s1)); \
    } \
    s0 += __shfl_xor(s0, 16); s0 += __shfl_xor(s0, 32); \
    s1 += __shfl_xor(s1, 16); s1 += __shfl_xor(s1, 32); \
    float x0 = s0 + lb0 + px0; \
    float x1 = s1 + lb1 + px1; \
    if (tid < 16) *(float2*)(outp + 2*(S)) = make_float2(x0 + off0, x1 + off1); \
    px0 = x0; px1 = x1; }

    // ================= decoder: 20 steps (starts reading buf1) =================
    #pragma unroll 1
    for (int sp = 0; sp < SDEC/2; ++sp) {
        STEP(1, px0, px1);  XPROJ(0, 2*sp);      // reads buf1, h-new -> buf0
        STEP(0, px0, px1);  XPROJ(1, 2*sp+1);    // reads buf0, h-new -> buf1
    }
#undef STEP
#undef XPROJ
}

extern "C" void kernel_launch(void* const* d_in, const int* in_sizes, int n_in,
                              void* d_out, int out_size, void* d_ws, size_t ws_size,
                              hipStream_t stream) {
    const float* input_seq = (const float*)d_in[0];
    const float* vel_W   = (const float*)d_in[1];
    const float* vel_b   = (const float*)d_in[2];
    const float* enc_Wih = (const float*)d_in[3];
    const float* enc_Whh = (const float*)d_in[4];
    const float* enc_bih = (const float*)d_in[5];
    const float* enc_bhh = (const float*)d_in[6];
    const float* dec_Wih = (const float*)d_in[7];
    const float* dec_Whh = (const float*)d_in[8];
    const float* dec_bih = (const float*)d_in[9];
    const float* dec_bhh = (const float*)d_in[10];
    const float* lin_W   = (const float*)d_in[11];
    const float* lin_b   = (const float*)d_in[12];
    float* out = (float*)d_out;

    int B = in_sizes[0] / (TSEQ * 2);     // 4096
    int blocks = B / 16;                  // 256 workgroups, 1 per CU
    gru_mfma_kernel<<<blocks, 256, 0, stream>>>(
        input_seq, vel_W, vel_b, enc_Wih, enc_Whh, enc_bih, enc_bhh,
        dec_Wih, dec_Whh, dec_bih, dec_bhh, lin_W, lin_b, out);
}